// Round 4
// baseline (605.553 us; speedup 1.0000x reference)
//
#include <hip/hip_runtime.h>
#include <hip/hip_bf16.h>

// GIN classifier. R3: per-layer fusion. Only gather crosses block boundaries,
// so each layer after the first is ONE kernel: gather+BN+ReLU -> LDS ->
// MFMA GEMM (w_lb, bias, relu) -> LDS -> MFMA GEMM (w_{l+1}a) -> coalesced out.
// Layer 3 fuses the pool. D1 = standalone K=384 bf16 MFMA GEMM.

#define N_NODES 100000
#define N_EDGES 800000
#define N_GRAPHS 128
#define NB_SCAN 391   // ceil(N_NODES/256)
#define LDP 168       // LDS row stride (bf16); ==40 mod 64 -> benign bank pattern
#define FLDP 68       // f32 LDS row stride for pool staging

typedef __bf16 bf16x8 __attribute__((ext_vector_type(8)));
typedef float f32x4 __attribute__((ext_vector_type(4)));
typedef unsigned short ushort_t;
typedef unsigned int uint_t;

static __device__ __forceinline__ ushort_t f2b(float f) {
    uint_t u = __builtin_bit_cast(uint_t, f);
    uint_t r = (u + 0x7fffu + ((u >> 16) & 1u)) >> 16;   // RNE
    return (ushort_t)r;
}
static __device__ __forceinline__ float b2f(ushort_t u) {
    return __builtin_bit_cast(float, (uint_t)u << 16);
}

// ------------- weight transpose+convert: Wt[c*K+k] = bf16(W[k*N+c]) ----------
__global__ __launch_bounds__(256) void wt_k(const float* __restrict__ W,
                                            ushort_t* __restrict__ Wt,
                                            int K, int N) {
    int t = blockIdx.x * 256 + threadIdx.x;
    if (t < K * N) {
        int k = t / N, c = t % N;
        Wt[c * K + k] = f2b(W[t]);
    }
}

// ---------------- standalone bf16 MFMA GEMM for layer-1 (A fp32, K=384) ------
template<int K, int N>
__global__ __launch_bounds__(256) void gemm_mfma_k(const float* __restrict__ A,
                                                   const ushort_t* __restrict__ Wt,
                                                   ushort_t* __restrict__ C, int M) {
    constexpr int BM = 128;
    constexpr int LDA = 40;
    constexpr int WN = 64;
    constexpr int MI = 4;
    constexpr int NJ = 4;
    __shared__ ushort_t Alds[BM * LDA];

    const int tid  = threadIdx.x;
    const int lane = tid & 63;
    const int wid  = tid >> 6;
    const int wrow = wid >> 1;
    const int wcol = wid & 1;
    const int l15  = lane & 15;
    const int kg   = lane >> 4;
    const int row0 = blockIdx.x * BM;

    f32x4 acc[MI][NJ];
    #pragma unroll
    for (int i = 0; i < MI; ++i)
        #pragma unroll
        for (int j = 0; j < NJ; ++j)
            acc[i][j] = f32x4{0.f, 0.f, 0.f, 0.f};

    for (int k0 = 0; k0 < K; k0 += 32) {
        __syncthreads();
        #pragma unroll
        for (int p = 0; p < 2; ++p) {
            int idx = tid + p * 256;
            int r = idx >> 2;
            int c8 = idx & 3;
            int gr = row0 + r;
            if (gr > M - 1) gr = M - 1;
            const float* pA = A + (size_t)gr * K + k0 + c8 * 8;
            float4 v0 = *reinterpret_cast<const float4*>(pA);
            float4 v1 = *reinterpret_cast<const float4*>(pA + 4);
            uint_t u0 = f2b(v0.x) | ((uint_t)f2b(v0.y) << 16);
            uint_t u1 = f2b(v0.z) | ((uint_t)f2b(v0.w) << 16);
            uint_t u2 = f2b(v1.x) | ((uint_t)f2b(v1.y) << 16);
            uint_t u3 = f2b(v1.z) | ((uint_t)f2b(v1.w) << 16);
            *reinterpret_cast<uint4*>(&Alds[r * LDA + c8 * 8]) = make_uint4(u0, u1, u2, u3);
        }
        __syncthreads();

        bf16x8 a[MI], b[NJ];
        #pragma unroll
        for (int i = 0; i < MI; ++i)
            a[i] = *reinterpret_cast<const bf16x8*>(&Alds[(wrow * 64 + i * 16 + l15) * LDA + kg * 8]);
        #pragma unroll
        for (int j = 0; j < NJ; ++j) {
            int col = wcol * WN + j * 16 + l15;
            b[j] = *reinterpret_cast<const bf16x8*>(Wt + (size_t)col * K + k0 + kg * 8);
        }
        #pragma unroll
        for (int i = 0; i < MI; ++i)
            #pragma unroll
            for (int j = 0; j < NJ; ++j)
                acc[i][j] = __builtin_amdgcn_mfma_f32_16x16x32_bf16(a[i], b[j], acc[i][j], 0, 0, 0);
    }

    #pragma unroll
    for (int i = 0; i < MI; ++i) {
        int rbase = row0 + wrow * 64 + i * 16 + kg * 4;
        #pragma unroll
        for (int j = 0; j < NJ; ++j) {
            int col = wcol * WN + j * 16 + l15;
            #pragma unroll
            for (int q = 0; q < 4; ++q) {
                int row = rbase + q;
                if (row < M) C[(size_t)row * N + col] = f2b(acc[i][j][q]);
            }
        }
    }
}

// ---------------- CSR build ----------------
__global__ __launch_bounds__(256) void hist_k(const int* __restrict__ dst,
                                              int* __restrict__ deg) {
    int e = blockIdx.x * 256 + threadIdx.x;
    if (e < N_EDGES) atomicAdd(&deg[dst[e]], 1);
}

__global__ __launch_bounds__(256) void scan1_k(const int* __restrict__ deg,
                                               int* __restrict__ tmp,
                                               int* __restrict__ bsum) {
    __shared__ int s[256];
    int i = blockIdx.x * 256 + threadIdx.x;
    int t = threadIdx.x;
    s[t] = (i < N_NODES) ? deg[i] : 0;
    __syncthreads();
    for (int off = 1; off < 256; off <<= 1) {
        int v = (t >= off) ? s[t - off] : 0;
        __syncthreads();
        s[t] += v;
        __syncthreads();
    }
    if (i < N_NODES) tmp[i] = s[t];
    if (t == 255) bsum[blockIdx.x] = s[255];
}

__global__ __launch_bounds__(512) void scan2_k(int* __restrict__ bsum) {
    __shared__ int s[512];
    int t = threadIdx.x;
    s[t] = (t < NB_SCAN) ? bsum[t] : 0;
    __syncthreads();
    for (int off = 1; off < 512; off <<= 1) {
        int v = (t >= off) ? s[t - off] : 0;
        __syncthreads();
        s[t] += v;
        __syncthreads();
    }
    if (t < NB_SCAN) bsum[t] = s[t];
}

__global__ __launch_bounds__(256) void scan3_k(const int* __restrict__ tmp,
                                               const int* __restrict__ deg,
                                               const int* __restrict__ bsum,
                                               int* __restrict__ row_start) {
    int i = blockIdx.x * 256 + threadIdx.x;
    if (i >= N_NODES) return;
    int boff = (blockIdx.x > 0) ? bsum[blockIdx.x - 1] : 0;
    row_start[i] = tmp[i] - deg[i] + boff;
}

__global__ __launch_bounds__(256) void fill_k(const int* __restrict__ src,
                                              const int* __restrict__ dst,
                                              int* __restrict__ row_start,
                                              int* __restrict__ csr_src) {
    int e = blockIdx.x * 256 + threadIdx.x;
    if (e >= N_EDGES) return;
    int idx = atomicAdd(&row_start[dst[e]], 1);
    csr_src[idx] = src[e];
}

// =================== fused layer kernel =====================================
// Per block of 128 nodes:
//   gather(Yin)+BN+ReLU -> LDS H -> GEMM1(Wb,bias1,relu) -> LDS ->
//   [HAS_G2: GEMM2(Wa2) -> LDS -> coalesced Yout write]
//   [else:   f32 LDS -> fused sorted-batch pool]
template<int N1, bool HAS_G2>
__global__ __launch_bounds__(256) void fused_layer_k(
        const ushort_t* __restrict__ Yin,
        const int* __restrict__ csr, const int* __restrict__ rend,
        const int* __restrict__ deg,
        const float* __restrict__ epsp, const float* __restrict__ ba,
        const float* __restrict__ g, const float* __restrict__ be,
        const float* __restrict__ mm, const float* __restrict__ vv,
        const ushort_t* __restrict__ Wb, const float* __restrict__ bias1,
        const ushort_t* __restrict__ Wa2,
        ushort_t* __restrict__ Yout,
        const int* __restrict__ batch, float* __restrict__ pooled,
        int M) {
    constexpr int WN1 = (N1 == 128) ? 64 : 32;
    constexpr int NJ1 = WN1 / 16;
    constexpr int MI = 4;
    __shared__ ushort_t Hlds[128 * LDP];
    float* Flds = (float*)Hlds;                 // pool staging view (f32, FLDP)

    const int tid   = threadIdx.x;
    const int lane  = tid & 63;
    const int wid   = tid >> 6;
    const int wrow  = wid >> 1;
    const int wcol  = wid & 1;
    const int l15   = lane & 15;
    const int kg    = lane >> 4;
    const int group = tid >> 4;                 // 0..15
    const int l16   = tid & 15;
    const int row0  = blockIdx.x * 128;

    // ---- phase G: gather + BN + ReLU -> Hlds ----
    {
        float ep = 1.0f + epsp[0];
        float sc[8], sh[8];
        #pragma unroll
        for (int jj = 0; jj < 8; ++jj) {
            int c = l16 * 8 + jj;
            float s = g[c] * rsqrtf(vv[c] + 1e-5f);
            sc[jj] = s;
            sh[jj] = (ba[c] - mm[c]) * s + be[c];
        }
        for (int nl = group; nl < 128; nl += 16) {
            int node = row0 + nl;
            uint4 packed = make_uint4(0, 0, 0, 0);
            if (node < M) {
                float acc[8] = {0.f, 0.f, 0.f, 0.f, 0.f, 0.f, 0.f, 0.f};
                int end = rend[node];
                int d = deg[node];
                for (int j2 = end - d; j2 < end; ++j2) {
                    int s = csr[j2];
                    uint4 w = *reinterpret_cast<const uint4*>(Yin + (size_t)s * 128 + l16 * 8);
                    acc[0] += b2f((ushort_t)(w.x & 0xffff)); acc[1] += b2f((ushort_t)(w.x >> 16));
                    acc[2] += b2f((ushort_t)(w.y & 0xffff)); acc[3] += b2f((ushort_t)(w.y >> 16));
                    acc[4] += b2f((ushort_t)(w.z & 0xffff)); acc[5] += b2f((ushort_t)(w.z >> 16));
                    acc[6] += b2f((ushort_t)(w.w & 0xffff)); acc[7] += b2f((ushort_t)(w.w >> 16));
                }
                uint4 ow = *reinterpret_cast<const uint4*>(Yin + (size_t)node * 128 + l16 * 8);
                float own[8];
                own[0] = b2f((ushort_t)(ow.x & 0xffff)); own[1] = b2f((ushort_t)(ow.x >> 16));
                own[2] = b2f((ushort_t)(ow.y & 0xffff)); own[3] = b2f((ushort_t)(ow.y >> 16));
                own[4] = b2f((ushort_t)(ow.z & 0xffff)); own[5] = b2f((ushort_t)(ow.z >> 16));
                own[6] = b2f((ushort_t)(ow.w & 0xffff)); own[7] = b2f((ushort_t)(ow.w >> 16));
                ushort_t r[8];
                #pragma unroll
                for (int jj = 0; jj < 8; ++jj) {
                    float t = sc[jj] * (ep * own[jj] + acc[jj]) + sh[jj];
                    r[jj] = f2b(fmaxf(t, 0.f));
                }
                packed.x = (uint_t)r[0] | ((uint_t)r[1] << 16);
                packed.y = (uint_t)r[2] | ((uint_t)r[3] << 16);
                packed.z = (uint_t)r[4] | ((uint_t)r[5] << 16);
                packed.w = (uint_t)r[6] | ((uint_t)r[7] << 16);
            }
            *reinterpret_cast<uint4*>(&Hlds[nl * LDP + l16 * 8]) = packed;
        }
    }
    __syncthreads();

    // ---- phase A: GEMM1 = H @ Wb  (K=128) ----
    bf16x8 a1[4][MI];
    #pragma unroll
    for (int kk = 0; kk < 4; ++kk)
        #pragma unroll
        for (int i = 0; i < MI; ++i)
            a1[kk][i] = *reinterpret_cast<const bf16x8*>(
                &Hlds[(wrow * 64 + i * 16 + l15) * LDP + kk * 32 + kg * 8]);

    f32x4 acc1[MI][NJ1];
    #pragma unroll
    for (int i = 0; i < MI; ++i)
        #pragma unroll
        for (int j = 0; j < NJ1; ++j)
            acc1[i][j] = f32x4{0.f, 0.f, 0.f, 0.f};

    #pragma unroll
    for (int kk = 0; kk < 4; ++kk)
        #pragma unroll
        for (int j = 0; j < NJ1; ++j) {
            int col = wcol * WN1 + j * 16 + l15;
            bf16x8 b = *reinterpret_cast<const bf16x8*>(Wb + (size_t)col * 128 + kk * 32 + kg * 8);
            #pragma unroll
            for (int i = 0; i < MI; ++i)
                acc1[i][j] = __builtin_amdgcn_mfma_f32_16x16x32_bf16(a1[kk][i], b, acc1[i][j], 0, 0, 0);
        }

    __syncthreads();   // all Hlds reads done

    // ---- phase B: X = relu(acc1 + bias1) -> LDS ----
    #pragma unroll
    for (int i = 0; i < MI; ++i)
        #pragma unroll
        for (int j = 0; j < NJ1; ++j) {
            int col = wcol * WN1 + j * 16 + l15;
            float bi = bias1[col];
            #pragma unroll
            for (int q = 0; q < 4; ++q) {
                int row = wrow * 64 + i * 16 + kg * 4 + q;
                float val = fmaxf(acc1[i][j][q] + bi, 0.f);
                if (HAS_G2) Hlds[row * LDP + col] = f2b(val);
                else        Flds[row * FLDP + col] = val;
            }
        }
    __syncthreads();

    if constexpr (HAS_G2) {
        // ---- phase C: GEMM2 = X @ Wa2 (128x128) ----
        bf16x8 a2[4][MI];
        #pragma unroll
        for (int kk = 0; kk < 4; ++kk)
            #pragma unroll
            for (int i = 0; i < MI; ++i)
                a2[kk][i] = *reinterpret_cast<const bf16x8*>(
                    &Hlds[(wrow * 64 + i * 16 + l15) * LDP + kk * 32 + kg * 8]);

        f32x4 acc2[MI][4];
        #pragma unroll
        for (int i = 0; i < MI; ++i)
            #pragma unroll
            for (int j = 0; j < 4; ++j)
                acc2[i][j] = f32x4{0.f, 0.f, 0.f, 0.f};

        #pragma unroll
        for (int kk = 0; kk < 4; ++kk)
            #pragma unroll
            for (int j = 0; j < 4; ++j) {
                int col = wcol * 64 + j * 16 + l15;
                bf16x8 b = *reinterpret_cast<const bf16x8*>(Wa2 + (size_t)col * 128 + kk * 32 + kg * 8);
                #pragma unroll
                for (int i = 0; i < MI; ++i)
                    acc2[i][j] = __builtin_amdgcn_mfma_f32_16x16x32_bf16(a2[kk][i], b, acc2[i][j], 0, 0, 0);
            }

        __syncthreads();   // all X reads done

        // ---- phase D: stage Y2 in LDS, coalesced full-line write ----
        #pragma unroll
        for (int i = 0; i < MI; ++i)
            #pragma unroll
            for (int j = 0; j < 4; ++j) {
                int col = wcol * 64 + j * 16 + l15;
                #pragma unroll
                for (int q = 0; q < 4; ++q) {
                    int row = wrow * 64 + i * 16 + kg * 4 + q;
                    Hlds[row * LDP + col] = f2b(acc2[i][j][q]);
                }
            }
        __syncthreads();
        #pragma unroll
        for (int p = 0; p < 8; ++p) {
            int r = p * 16 + group;
            int gr = row0 + r;
            if (gr < M)
                *reinterpret_cast<uint4*>(Yout + (size_t)gr * 128 + l16 * 8) =
                    *reinterpret_cast<const uint4*>(&Hlds[r * LDP + l16 * 8]);
        }
    } else {
        // ---- pool: sorted-batch run-length over f32 LDS rows ----
        int col = tid & 63;
        int q = tid >> 6;
        float acc = 0.f;
        int cur = -1;
        for (int rr = 0; rr < 32; ++rr) {
            int r = q * 32 + rr;
            int gr = row0 + r;
            if (gr >= M) break;
            int b = batch[gr];
            if (b != cur) {
                if (cur >= 0) atomicAdd(&pooled[cur * 64 + col], acc);
                acc = 0.f;
                cur = b;
            }
            acc += Flds[r * FLDP + col];
        }
        if (cur >= 0) atomicAdd(&pooled[cur * 64 + col], acc);
    }
}

// ---------------- classifier ----------------
__global__ __launch_bounds__(256) void classifier_k(const float* __restrict__ pooled,
                                                    const float* __restrict__ wc,
                                                    const float* __restrict__ bc,
                                                    float* __restrict__ out) {
    int t = threadIdx.x;
    int gidx = t >> 1, c = t & 1;
    float s = bc[c];
    #pragma unroll
    for (int k = 0; k < 64; ++k)
        s += pooled[gidx * 64 + k] * wc[k * 2 + c];
    out[gidx * 2 + c] = s;
}

extern "C" void kernel_launch(void* const* d_in, const int* in_sizes, int n_in,
                              void* d_out, int out_size, void* d_ws, size_t ws_size,
                              hipStream_t stream) {
    const float* x     = (const float*)d_in[0];
    const int*   ei    = (const int*)d_in[1];
    const int*   src   = ei;
    const int*   dst   = ei + N_EDGES;
    const int*   batch = (const int*)d_in[2];
    const float* eps1 = (const float*)d_in[3];
    const float* w1a  = (const float*)d_in[4];
    const float* b1a  = (const float*)d_in[5];
    const float* g1   = (const float*)d_in[6];
    const float* be1  = (const float*)d_in[7];
    const float* m1   = (const float*)d_in[8];
    const float* v1   = (const float*)d_in[9];
    const float* w1b  = (const float*)d_in[10];
    const float* b1b  = (const float*)d_in[11];
    const float* eps2 = (const float*)d_in[12];
    const float* w2a  = (const float*)d_in[13];
    const float* b2a  = (const float*)d_in[14];
    const float* g2   = (const float*)d_in[15];
    const float* be2  = (const float*)d_in[16];
    const float* m2   = (const float*)d_in[17];
    const float* v2   = (const float*)d_in[18];
    const float* w2b  = (const float*)d_in[19];
    const float* b2b  = (const float*)d_in[20];
    const float* eps3 = (const float*)d_in[21];
    const float* w3a  = (const float*)d_in[22];
    const float* b3a  = (const float*)d_in[23];
    const float* g3   = (const float*)d_in[24];
    const float* be3  = (const float*)d_in[25];
    const float* m3   = (const float*)d_in[26];
    const float* v3   = (const float*)d_in[27];
    const float* w3b  = (const float*)d_in[28];
    const float* b3b  = (const float*)d_in[29];
    const float* wc   = (const float*)d_in[30];
    const float* bc   = (const float*)d_in[31];
    float* out = (float*)d_out;

    // workspace layout
    ushort_t* Y = (ushort_t*)d_ws;             // [100000,128] bf16
    ushort_t* H = Y + 12800000;                // [100000,128] bf16
    ushort_t* wt1a = H + 12800000;             // 384*128
    ushort_t* wt1b = wt1a + 49152;             // 128*128
    ushort_t* wt2a = wt1b + 16384;
    ushort_t* wt2b = wt2a + 16384;
    ushort_t* wt3a = wt2b + 16384;
    ushort_t* wt3b = wt3a + 16384;             // 64*128
    float* pooled = (float*)(wt3b + 8192);     // [128,64]
    int* ideg = (int*)(pooled + 8192);         // [100000]
    int* irow = ideg + N_NODES;
    int* itmp = irow + N_NODES;
    int* icsr = itmp + N_NODES;                // [800000]
    int* ibsum = icsr + N_EDGES;               // [391]

    const int M = N_NODES;
    const int gGemm = (M + 127) / 128;         // 782
    const int gEdge = (N_EDGES + 255) / 256;   // 3125
    const int gNode = NB_SCAN;                 // 391

    // ---- weight transpose+convert (tiny) ----
    wt_k<<<192, 256, 0, stream>>>(w1a, wt1a, 384, 128);
    wt_k<<<64, 256, 0, stream>>>(w1b, wt1b, 128, 128);
    wt_k<<<64, 256, 0, stream>>>(w2a, wt2a, 128, 128);
    wt_k<<<64, 256, 0, stream>>>(w2b, wt2b, 128, 128);
    wt_k<<<64, 256, 0, stream>>>(w3a, wt3a, 128, 128);
    wt_k<<<32, 256, 0, stream>>>(w3b, wt3b, 128, 64);

    // ---- build CSR ----
    hipMemsetAsync(ideg, 0, N_NODES * sizeof(int), stream);
    hist_k<<<gEdge, 256, 0, stream>>>(dst, ideg);
    scan1_k<<<gNode, 256, 0, stream>>>(ideg, itmp, ibsum);
    scan2_k<<<1, 512, 0, stream>>>(ibsum);
    scan3_k<<<gNode, 256, 0, stream>>>(itmp, ideg, ibsum, irow);
    fill_k<<<gEdge, 256, 0, stream>>>(src, dst, irow, icsr);
    hipMemsetAsync(pooled, 0, (size_t)N_GRAPHS * 64 * sizeof(float), stream);

    // ---- D1: Y1 = x @ w1a ----
    gemm_mfma_k<384, 128><<<gGemm, 256, 0, stream>>>(x, wt1a, Y, M);

    // ---- D2: layer1 tail + layer2 head ----
    fused_layer_k<128, true><<<gGemm, 256, 0, stream>>>(
        Y, icsr, irow, ideg, eps1, b1a, g1, be1, m1, v1,
        wt1b, b1b, wt2a, H, nullptr, nullptr, M);

    // ---- D3: layer2 tail + layer3 head ----
    fused_layer_k<128, true><<<gGemm, 256, 0, stream>>>(
        H, icsr, irow, ideg, eps2, b2a, g2, be2, m2, v2,
        wt2b, b2b, wt3a, Y, nullptr, nullptr, M);

    // ---- D4: layer3 tail + pool ----
    fused_layer_k<64, false><<<gGemm, 256, 0, stream>>>(
        Y, icsr, irow, ideg, eps3, b3a, g3, be3, m3, v3,
        wt3b, b3b, nullptr, nullptr, batch, pooled, M);

    // ---- classifier ----
    classifier_k<<<1, 256, 0, stream>>>(pooled, wc, bc, out);
}

// Round 5
// 419.033 us; speedup vs baseline: 1.4451x; 1.4451x over previous
//
#include <hip/hip_runtime.h>
#include <hip/hip_bf16.h>

// GIN classifier. R4: split gather from GEMMs.
//  - gather_bn_k: one wave/node, 4 neighbor-slots in parallel, no LDS,
//    8192 waves -> MLP-bound not latency-bound. BN+ReLU fused.
//  - mlp_k: H @ Wb (+bias,relu) @ Wa2 in one kernel, K=128 unrolled, 3 barriers.
//  - gemm1_k: x(fp32) @ w1a, BM=64, BK=128.

#define N_NODES 100000
#define N_EDGES 800000
#define N_GRAPHS 128
#define NB_SCAN 391   // ceil(N_NODES/256)
#define LDP 136       // bf16 LDS row stride: 2-way bank alias only (free)
#define FLDP 68       // f32 row stride for pool staging

typedef __bf16 bf16x8 __attribute__((ext_vector_type(8)));
typedef float f32x4 __attribute__((ext_vector_type(4)));
typedef unsigned short ushort_t;
typedef unsigned int uint_t;

static __device__ __forceinline__ ushort_t f2b(float f) {
    uint_t u = __builtin_bit_cast(uint_t, f);
    uint_t r = (u + 0x7fffu + ((u >> 16) & 1u)) >> 16;   // RNE
    return (ushort_t)r;
}
static __device__ __forceinline__ float b2f(ushort_t u) {
    return __builtin_bit_cast(float, (uint_t)u << 16);
}

// ------------- weight transpose+convert: Wt[c*K+k] = bf16(W[k*N+c]) ----------
__global__ __launch_bounds__(256) void wt_k(const float* __restrict__ W,
                                            ushort_t* __restrict__ Wt,
                                            int K, int N) {
    int t = blockIdx.x * 256 + threadIdx.x;
    if (t < K * N) {
        int k = t / N, c = t % N;
        Wt[c * K + k] = f2b(W[t]);
    }
}

// ---------------- D1: C[M,128] = bf16(A fp32 [M,384]) @ Wt ------------------
template<int K>
__global__ __launch_bounds__(256) void gemm1_k(const float* __restrict__ A,
                                               const ushort_t* __restrict__ Wt,
                                               ushort_t* __restrict__ C, int M) {
    constexpr int BM = 64;
    __shared__ ushort_t Al[BM * LDP];

    const int tid  = threadIdx.x;
    const int lane = tid & 63;
    const int wid  = tid >> 6;
    const int wrow = wid >> 1;              // 0..1 (32-row halves)
    const int wcol = wid & 1;               // 0..1 (64-col halves)
    const int l15  = lane & 15;
    const int kg   = lane >> 4;
    const int row0 = blockIdx.x * BM;

    f32x4 acc[2][4];
    #pragma unroll
    for (int i = 0; i < 2; ++i)
        #pragma unroll
        for (int j = 0; j < 4; ++j)
            acc[i][j] = f32x4{0.f, 0.f, 0.f, 0.f};

    const int r  = tid >> 2;                // staging row 0..63
    const int cc = (tid & 3) * 32;          // staging col chunk

    for (int k0 = 0; k0 < K; k0 += 128) {
        __syncthreads();
        {
            int gr = row0 + r;
            if (gr > M - 1) gr = M - 1;
            const float* pA = A + (size_t)gr * K + k0 + cc;
            float4 v[8];
            #pragma unroll
            for (int p = 0; p < 8; ++p)
                v[p] = *reinterpret_cast<const float4*>(pA + p * 4);
            uint_t u[16];
            #pragma unroll
            for (int p = 0; p < 8; ++p) {
                u[2 * p]     = (uint_t)f2b(v[p].x) | ((uint_t)f2b(v[p].y) << 16);
                u[2 * p + 1] = (uint_t)f2b(v[p].z) | ((uint_t)f2b(v[p].w) << 16);
            }
            uint4* dst = reinterpret_cast<uint4*>(&Al[r * LDP + cc]);
            dst[0] = make_uint4(u[0], u[1], u[2], u[3]);
            dst[1] = make_uint4(u[4], u[5], u[6], u[7]);
            dst[2] = make_uint4(u[8], u[9], u[10], u[11]);
            dst[3] = make_uint4(u[12], u[13], u[14], u[15]);
        }
        __syncthreads();

        #pragma unroll
        for (int kk = 0; kk < 4; ++kk) {
            bf16x8 a0 = *reinterpret_cast<const bf16x8*>(&Al[(wrow * 32 + l15) * LDP + kk * 32 + kg * 8]);
            bf16x8 a1 = *reinterpret_cast<const bf16x8*>(&Al[(wrow * 32 + 16 + l15) * LDP + kk * 32 + kg * 8]);
            #pragma unroll
            for (int j = 0; j < 4; ++j) {
                int col = wcol * 64 + j * 16 + l15;
                bf16x8 b = *reinterpret_cast<const bf16x8*>(Wt + (size_t)col * K + k0 + kk * 32 + kg * 8);
                acc[0][j] = __builtin_amdgcn_mfma_f32_16x16x32_bf16(a0, b, acc[0][j], 0, 0, 0);
                acc[1][j] = __builtin_amdgcn_mfma_f32_16x16x32_bf16(a1, b, acc[1][j], 0, 0, 0);
            }
        }
    }

    // epilogue: stage bf16 rows in LDS, full-line coalesced store
    __syncthreads();
    #pragma unroll
    for (int i = 0; i < 2; ++i)
        #pragma unroll
        for (int j = 0; j < 4; ++j) {
            int col = wcol * 64 + j * 16 + l15;
            #pragma unroll
            for (int q = 0; q < 4; ++q) {
                int row = wrow * 32 + i * 16 + kg * 4 + q;
                Al[row * LDP + col] = f2b(acc[i][j][q]);
            }
        }
    __syncthreads();
    #pragma unroll
    for (int p = 0; p < 4; ++p) {
        int idx = tid + p * 256;
        int rr = idx >> 4, c16 = idx & 15;
        int gr = row0 + rr;
        if (gr < M)
            *reinterpret_cast<uint4*>(C + (size_t)gr * 128 + c16 * 8) =
                *reinterpret_cast<const uint4*>(&Al[rr * LDP + c16 * 8]);
    }
}

// ---------------- CSR build ----------------
__global__ __launch_bounds__(256) void hist_k(const int* __restrict__ dst,
                                              int* __restrict__ deg) {
    int e = blockIdx.x * 256 + threadIdx.x;
    if (e < N_EDGES) atomicAdd(&deg[dst[e]], 1);
}

__global__ __launch_bounds__(256) void scan1_k(const int* __restrict__ deg,
                                               int* __restrict__ tmp,
                                               int* __restrict__ bsum) {
    __shared__ int s[256];
    int i = blockIdx.x * 256 + threadIdx.x;
    int t = threadIdx.x;
    s[t] = (i < N_NODES) ? deg[i] : 0;
    __syncthreads();
    for (int off = 1; off < 256; off <<= 1) {
        int v = (t >= off) ? s[t - off] : 0;
        __syncthreads();
        s[t] += v;
        __syncthreads();
    }
    if (i < N_NODES) tmp[i] = s[t];
    if (t == 255) bsum[blockIdx.x] = s[255];
}

__global__ __launch_bounds__(512) void scan2_k(int* __restrict__ bsum) {
    __shared__ int s[512];
    int t = threadIdx.x;
    s[t] = (t < NB_SCAN) ? bsum[t] : 0;
    __syncthreads();
    for (int off = 1; off < 512; off <<= 1) {
        int v = (t >= off) ? s[t - off] : 0;
        __syncthreads();
        s[t] += v;
        __syncthreads();
    }
    if (t < NB_SCAN) bsum[t] = s[t];
}

__global__ __launch_bounds__(256) void scan3_k(const int* __restrict__ tmp,
                                               const int* __restrict__ deg,
                                               const int* __restrict__ bsum,
                                               int* __restrict__ row_start) {
    int i = blockIdx.x * 256 + threadIdx.x;
    if (i >= N_NODES) return;
    int boff = (blockIdx.x > 0) ? bsum[blockIdx.x - 1] : 0;
    row_start[i] = tmp[i] - deg[i] + boff;
}

__global__ __launch_bounds__(256) void fill_k(const int* __restrict__ src,
                                              const int* __restrict__ dst,
                                              int* __restrict__ row_start,
                                              int* __restrict__ csr_src) {
    int e = blockIdx.x * 256 + threadIdx.x;
    if (e >= N_EDGES) return;
    int idx = atomicAdd(&row_start[dst[e]], 1);
    csr_src[idx] = src[e];
}

// ---------- gather + BN + ReLU, one wave per node, 4 neighbor slots ----------
__global__ __launch_bounds__(256) void gather_bn_k(
        const ushort_t* __restrict__ Yin,
        const int* __restrict__ csr, const int* __restrict__ rend,
        const int* __restrict__ deg,
        const float* __restrict__ epsp, const float* __restrict__ ba,
        const float* __restrict__ g, const float* __restrict__ be,
        const float* __restrict__ mm, const float* __restrict__ vv,
        ushort_t* __restrict__ H, int nwaves) {
    const int gwid = (blockIdx.x * 256 + threadIdx.x) >> 6;
    const int lane = threadIdx.x & 63;
    const int l15  = lane & 15;
    const int slot = lane >> 4;
    const int c0   = l15 * 8;

    float ep = 1.0f + epsp[0];
    float sc[8], sh[8];
    #pragma unroll
    for (int jj = 0; jj < 8; ++jj) {
        int c = c0 + jj;
        float s = g[c] * rsqrtf(vv[c] + 1e-5f);
        sc[jj] = s;
        sh[jj] = (ba[c] - mm[c]) * s + be[c];
    }

    for (int node = gwid; node < N_NODES; node += nwaves) {
        int end = rend[node];
        int d = deg[node];
        int st = end - d;
        // own row load issued early (used after the loop)
        uint4 ow = *reinterpret_cast<const uint4*>(Yin + (size_t)node * 128 + c0);
        int nlim = (d > 64) ? 64 : d;
        int nb = (lane < nlim) ? csr[st + lane] : 0;

        float acc[8] = {0.f, 0.f, 0.f, 0.f, 0.f, 0.f, 0.f, 0.f};
        for (int j0 = 0; j0 < nlim; j0 += 8) {
            int jA = j0 + slot;
            int jB = j0 + 4 + slot;
            int ia = __shfl(nb, jA & 63);
            int ib = __shfl(nb, jB & 63);
            uint4 wa = *reinterpret_cast<const uint4*>(Yin + (size_t)ia * 128 + c0);
            uint4 wb = *reinterpret_cast<const uint4*>(Yin + (size_t)ib * 128 + c0);
            float fa = (jA < nlim) ? 1.f : 0.f;
            float fb = (jB < nlim) ? 1.f : 0.f;
            uint_t ua[4] = {wa.x, wa.y, wa.z, wa.w};
            uint_t ub[4] = {wb.x, wb.y, wb.z, wb.w};
            #pragma unroll
            for (int p = 0; p < 4; ++p) {
                acc[2 * p]     += fa * b2f((ushort_t)(ua[p] & 0xffff));
                acc[2 * p + 1] += fa * b2f((ushort_t)(ua[p] >> 16));
                acc[2 * p]     += fb * b2f((ushort_t)(ub[p] & 0xffff));
                acc[2 * p + 1] += fb * b2f((ushort_t)(ub[p] >> 16));
            }
        }
        // rare: degree > 64 remainder (slot 0 only, summed by reduction below)
        for (int j = st + 64; j < end; ++j) {
            if (slot == 0) {
                int idx = csr[j];
                uint4 w = *reinterpret_cast<const uint4*>(Yin + (size_t)idx * 128 + c0);
                uint_t uw[4] = {w.x, w.y, w.z, w.w};
                #pragma unroll
                for (int p = 0; p < 4; ++p) {
                    acc[2 * p]     += b2f((ushort_t)(uw[p] & 0xffff));
                    acc[2 * p + 1] += b2f((ushort_t)(uw[p] >> 16));
                }
            }
        }
        // reduce across the 4 slots
        #pragma unroll
        for (int jj = 0; jj < 8; ++jj) {
            acc[jj] += __shfl_xor(acc[jj], 16);
            acc[jj] += __shfl_xor(acc[jj], 32);
        }
        // BN + ReLU, pack, slot 0 stores the row
        uint_t uo[4] = {ow.x, ow.y, ow.z, ow.w};
        ushort_t rr[8];
        #pragma unroll
        for (int p = 0; p < 4; ++p) {
            float o0 = b2f((ushort_t)(uo[p] & 0xffff));
            float o1 = b2f((ushort_t)(uo[p] >> 16));
            float t0 = sc[2 * p] * (ep * o0 + acc[2 * p]) + sh[2 * p];
            float t1 = sc[2 * p + 1] * (ep * o1 + acc[2 * p + 1]) + sh[2 * p + 1];
            rr[2 * p]     = f2b(fmaxf(t0, 0.f));
            rr[2 * p + 1] = f2b(fmaxf(t1, 0.f));
        }
        if (slot == 0) {
            uint4 packed;
            packed.x = (uint_t)rr[0] | ((uint_t)rr[1] << 16);
            packed.y = (uint_t)rr[2] | ((uint_t)rr[3] << 16);
            packed.z = (uint_t)rr[4] | ((uint_t)rr[5] << 16);
            packed.w = (uint_t)rr[6] | ((uint_t)rr[7] << 16);
            *reinterpret_cast<uint4*>(H + (size_t)node * 128 + c0) = packed;
        }
    }
}

// -------- MLP pair: X=relu(H@Wb+bias); TAIL? pool(X) : Yout = X@Wa2 ----------
template<bool TAIL>
__global__ __launch_bounds__(256) void mlp_k(const ushort_t* __restrict__ Hin,
                                             const ushort_t* __restrict__ Wb,
                                             const float* __restrict__ bias1,
                                             const ushort_t* __restrict__ Wa2,
                                             ushort_t* __restrict__ Yout,
                                             const int* __restrict__ batch,
                                             float* __restrict__ pooled, int M) {
    constexpr int BM = 64;
    constexpr int NJ1 = TAIL ? 2 : 4;       // N1 = 64 or 128
    __shared__ ushort_t Hl[BM * LDP];
    __shared__ ushort_t Xl[BM * LDP];       // also f32 pool staging [64][FLDP]
    float* Fl = (float*)Xl;

    const int tid  = threadIdx.x;
    const int lane = tid & 63;
    const int wid  = tid >> 6;
    const int wrow = wid >> 1;
    const int wcol = wid & 1;
    const int l15  = lane & 15;
    const int kg   = lane >> 4;
    const int row0 = blockIdx.x * BM;

    // stage H tile (coalesced)
    #pragma unroll
    for (int p = 0; p < 4; ++p) {
        int idx = tid + p * 256;
        int r = idx >> 4, c16 = idx & 15;
        int gr = row0 + r;
        if (gr > M - 1) gr = M - 1;
        *reinterpret_cast<uint4*>(&Hl[r * LDP + c16 * 8]) =
            *reinterpret_cast<const uint4*>(Hin + (size_t)gr * 128 + c16 * 8);
    }
    __syncthreads();

    // GEMM1: K=128
    f32x4 acc1[2][NJ1];
    #pragma unroll
    for (int i = 0; i < 2; ++i)
        #pragma unroll
        for (int j = 0; j < NJ1; ++j)
            acc1[i][j] = f32x4{0.f, 0.f, 0.f, 0.f};
    #pragma unroll
    for (int kk = 0; kk < 4; ++kk) {
        bf16x8 a0 = *reinterpret_cast<const bf16x8*>(&Hl[(wrow * 32 + l15) * LDP + kk * 32 + kg * 8]);
        bf16x8 a1 = *reinterpret_cast<const bf16x8*>(&Hl[(wrow * 32 + 16 + l15) * LDP + kk * 32 + kg * 8]);
        #pragma unroll
        for (int j = 0; j < NJ1; ++j) {
            int col = wcol * (16 * NJ1) + j * 16 + l15;
            bf16x8 b = *reinterpret_cast<const bf16x8*>(Wb + (size_t)col * 128 + kk * 32 + kg * 8);
            acc1[0][j] = __builtin_amdgcn_mfma_f32_16x16x32_bf16(a0, b, acc1[0][j], 0, 0, 0);
            acc1[1][j] = __builtin_amdgcn_mfma_f32_16x16x32_bf16(a1, b, acc1[1][j], 0, 0, 0);
        }
    }

    if constexpr (TAIL) {
        // X (f32) -> Fl, then sorted-batch pool
        #pragma unroll
        for (int i = 0; i < 2; ++i)
            #pragma unroll
            for (int j = 0; j < NJ1; ++j) {
                int col = wcol * 32 + j * 16 + l15;
                float bi = bias1[col];
                #pragma unroll
                for (int q = 0; q < 4; ++q) {
                    int row = wrow * 32 + i * 16 + kg * 4 + q;
                    Fl[row * FLDP + col] = fmaxf(acc1[i][j][q] + bi, 0.f);
                }
            }
        __syncthreads();
        int col = tid & 63;
        int qq  = tid >> 6;
        float a = 0.f;
        int cur = -1;
        for (int rr = 0; rr < 16; ++rr) {
            int r = qq * 16 + rr;
            int gr = row0 + r;
            if (gr >= M) break;
            int b = batch[gr];
            if (b != cur) {
                if (cur >= 0) atomicAdd(&pooled[cur * 64 + col], a);
                a = 0.f;
                cur = b;
            }
            a += Fl[r * FLDP + col];
        }
        if (cur >= 0) atomicAdd(&pooled[cur * 64 + col], a);
    } else {
        // X (bf16) -> Xl
        #pragma unroll
        for (int i = 0; i < 2; ++i)
            #pragma unroll
            for (int j = 0; j < NJ1; ++j) {
                int col = wcol * 64 + j * 16 + l15;
                float bi = bias1[col];
                #pragma unroll
                for (int q = 0; q < 4; ++q) {
                    int row = wrow * 32 + i * 16 + kg * 4 + q;
                    Xl[row * LDP + col] = f2b(fmaxf(acc1[i][j][q] + bi, 0.f));
                }
            }
        __syncthreads();

        // GEMM2: Y = X @ Wa2 (128x128)
        f32x4 acc2[2][4];
        #pragma unroll
        for (int i = 0; i < 2; ++i)
            #pragma unroll
            for (int j = 0; j < 4; ++j)
                acc2[i][j] = f32x4{0.f, 0.f, 0.f, 0.f};
        #pragma unroll
        for (int kk = 0; kk < 4; ++kk) {
            bf16x8 a0 = *reinterpret_cast<const bf16x8*>(&Xl[(wrow * 32 + l15) * LDP + kk * 32 + kg * 8]);
            bf16x8 a1 = *reinterpret_cast<const bf16x8*>(&Xl[(wrow * 32 + 16 + l15) * LDP + kk * 32 + kg * 8]);
            #pragma unroll
            for (int j = 0; j < 4; ++j) {
                int col = wcol * 64 + j * 16 + l15;
                bf16x8 b = *reinterpret_cast<const bf16x8*>(Wa2 + (size_t)col * 128 + kk * 32 + kg * 8);
                acc2[0][j] = __builtin_amdgcn_mfma_f32_16x16x32_bf16(a0, b, acc2[0][j], 0, 0, 0);
                acc2[1][j] = __builtin_amdgcn_mfma_f32_16x16x32_bf16(a1, b, acc2[1][j], 0, 0, 0);
            }
        }
        // stage into Hl (all Hl reads finished before the Xl barrier), store
        #pragma unroll
        for (int i = 0; i < 2; ++i)
            #pragma unroll
            for (int j = 0; j < 4; ++j) {
                int col = wcol * 64 + j * 16 + l15;
                #pragma unroll
                for (int q = 0; q < 4; ++q) {
                    int row = wrow * 32 + i * 16 + kg * 4 + q;
                    Hl[row * LDP + col] = f2b(acc2[i][j][q]);
                }
            }
        __syncthreads();
        #pragma unroll
        for (int p = 0; p < 4; ++p) {
            int idx = tid + p * 256;
            int r = idx >> 4, c16 = idx & 15;
            int gr = row0 + r;
            if (gr < M)
                *reinterpret_cast<uint4*>(Yout + (size_t)gr * 128 + c16 * 8) =
                    *reinterpret_cast<const uint4*>(&Hl[r * LDP + c16 * 8]);
        }
    }
}

// ---------------- classifier ----------------
__global__ __launch_bounds__(256) void classifier_k(const float* __restrict__ pooled,
                                                    const float* __restrict__ wc,
                                                    const float* __restrict__ bc,
                                                    float* __restrict__ out) {
    int t = threadIdx.x;
    int gidx = t >> 1, c = t & 1;
    float s = bc[c];
    #pragma unroll
    for (int k = 0; k < 64; ++k)
        s += pooled[gidx * 64 + k] * wc[k * 2 + c];
    out[gidx * 2 + c] = s;
}

extern "C" void kernel_launch(void* const* d_in, const int* in_sizes, int n_in,
                              void* d_out, int out_size, void* d_ws, size_t ws_size,
                              hipStream_t stream) {
    const float* x     = (const float*)d_in[0];
    const int*   ei    = (const int*)d_in[1];
    const int*   src   = ei;
    const int*   dst   = ei + N_EDGES;
    const int*   batch = (const int*)d_in[2];
    const float* eps1 = (const float*)d_in[3];
    const float* w1a  = (const float*)d_in[4];
    const float* b1a  = (const float*)d_in[5];
    const float* g1   = (const float*)d_in[6];
    const float* be1  = (const float*)d_in[7];
    const float* m1   = (const float*)d_in[8];
    const float* v1   = (const float*)d_in[9];
    const float* w1b  = (const float*)d_in[10];
    const float* b1b  = (const float*)d_in[11];
    const float* eps2 = (const float*)d_in[12];
    const float* w2a  = (const float*)d_in[13];
    const float* b2a  = (const float*)d_in[14];
    const float* g2   = (const float*)d_in[15];
    const float* be2  = (const float*)d_in[16];
    const float* m2   = (const float*)d_in[17];
    const float* v2   = (const float*)d_in[18];
    const float* w2b  = (const float*)d_in[19];
    const float* b2b  = (const float*)d_in[20];
    const float* eps3 = (const float*)d_in[21];
    const float* w3a  = (const float*)d_in[22];
    const float* b3a  = (const float*)d_in[23];
    const float* g3   = (const float*)d_in[24];
    const float* be3  = (const float*)d_in[25];
    const float* m3   = (const float*)d_in[26];
    const float* v3   = (const float*)d_in[27];
    const float* w3b  = (const float*)d_in[28];
    const float* b3b  = (const float*)d_in[29];
    const float* wc   = (const float*)d_in[30];
    const float* bc   = (const float*)d_in[31];
    float* out = (float*)d_out;

    // workspace layout
    ushort_t* Y = (ushort_t*)d_ws;             // [100000,128] bf16
    ushort_t* H = Y + 12800000;                // [100000,128] bf16
    ushort_t* wt1a = H + 12800000;             // 384*128
    ushort_t* wt1b = wt1a + 49152;             // 128*128
    ushort_t* wt2a = wt1b + 16384;
    ushort_t* wt2b = wt2a + 16384;
    ushort_t* wt3a = wt2b + 16384;
    ushort_t* wt3b = wt3a + 16384;             // 64*128
    float* pooled = (float*)(wt3b + 8192);     // [128,64]
    int* ideg = (int*)(pooled + 8192);         // [100000]
    int* irow = ideg + N_NODES;
    int* itmp = irow + N_NODES;
    int* icsr = itmp + N_NODES;                // [800000]
    int* ibsum = icsr + N_EDGES;               // [391]

    const int M = N_NODES;
    const int gGemm = (M + 63) / 64;           // 1563
    const int gEdge = (N_EDGES + 255) / 256;   // 3125
    const int gNode = NB_SCAN;                 // 391
    const int gGath = 2048;                    // 8192 waves
    const int nwaves = gGath * 4;

    // ---- weight transpose+convert (tiny) ----
    wt_k<<<192, 256, 0, stream>>>(w1a, wt1a, 384, 128);
    wt_k<<<64, 256, 0, stream>>>(w1b, wt1b, 128, 128);
    wt_k<<<64, 256, 0, stream>>>(w2a, wt2a, 128, 128);
    wt_k<<<64, 256, 0, stream>>>(w2b, wt2b, 128, 128);
    wt_k<<<64, 256, 0, stream>>>(w3a, wt3a, 128, 128);
    wt_k<<<32, 256, 0, stream>>>(w3b, wt3b, 128, 64);

    // ---- build CSR ----
    hipMemsetAsync(ideg, 0, N_NODES * sizeof(int), stream);
    hist_k<<<gEdge, 256, 0, stream>>>(dst, ideg);
    scan1_k<<<gNode, 256, 0, stream>>>(ideg, itmp, ibsum);
    scan2_k<<<1, 512, 0, stream>>>(ibsum);
    scan3_k<<<gNode, 256, 0, stream>>>(itmp, ideg, ibsum, irow);
    fill_k<<<gEdge, 256, 0, stream>>>(src, dst, irow, icsr);
    hipMemsetAsync(pooled, 0, (size_t)N_GRAPHS * 64 * sizeof(float), stream);

    // ---- D1: Y1 = x @ w1a ----
    gemm1_k<384><<<gGemm, 256, 0, stream>>>(x, wt1a, Y, M);

    // ---- layer 1 ----
    gather_bn_k<<<gGath, 256, 0, stream>>>(Y, icsr, irow, ideg, eps1, b1a, g1, be1, m1, v1, H, nwaves);
    mlp_k<false><<<gGemm, 256, 0, stream>>>(H, wt1b, b1b, wt2a, Y, nullptr, nullptr, M);

    // ---- layer 2 ----
    gather_bn_k<<<gGath, 256, 0, stream>>>(Y, icsr, irow, ideg, eps2, b2a, g2, be2, m2, v2, H, nwaves);
    mlp_k<false><<<gGemm, 256, 0, stream>>>(H, wt2b, b2b, wt3a, Y, nullptr, nullptr, M);

    // ---- layer 3 ----
    gather_bn_k<<<gGath, 256, 0, stream>>>(Y, icsr, irow, ideg, eps3, b3a, g3, be3, m3, v3, H, nwaves);
    mlp_k<true><<<gGemm, 256, 0, stream>>>(H, wt3b, b3b, nullptr, nullptr, batch, pooled, M);

    // ---- classifier ----
    classifier_k<<<1, 256, 0, stream>>>(pooled, wc, bc, out);
}

// Round 6
// 411.857 us; speedup vs baseline: 1.4703x; 1.0174x over previous
//
#include <hip/hip_runtime.h>
#include <hip/hip_bf16.h>

// GIN classifier. R5: gemm1 rebuilt with single-burst full-K LDS staging
// (one barrier pair, 24 coalesced loads in flight per thread); 6 weight
// transposes merged into one kernel. Gather/mlp/CSR unchanged from R4.

#define N_NODES 100000
#define N_EDGES 800000
#define N_GRAPHS 128
#define NB_SCAN 391   // ceil(N_NODES/256)
#define LDP 136       // bf16 LDS row stride (mlp): 2-way bank alias only (free)
#define FLDP 68       // f32 row stride for pool staging
#define LDA1 392      // gemm1 LDS row stride (bf16): mult of 8, 2-way alias reads

typedef __bf16 bf16x8 __attribute__((ext_vector_type(8)));
typedef float f32x4 __attribute__((ext_vector_type(4)));
typedef unsigned short ushort_t;
typedef unsigned int uint_t;

static __device__ __forceinline__ ushort_t f2b(float f) {
    uint_t u = __builtin_bit_cast(uint_t, f);
    uint_t r = (u + 0x7fffu + ((u >> 16) & 1u)) >> 16;   // RNE
    return (ushort_t)r;
}
static __device__ __forceinline__ float b2f(ushort_t u) {
    return __builtin_bit_cast(float, (uint_t)u << 16);
}

// ------------- all weight transposes in one kernel: Wt[c*K+k] = bf16(W[k*N+c])
__global__ __launch_bounds__(256) void wt_all_k(
        const float* __restrict__ w1a, const float* __restrict__ w1b,
        const float* __restrict__ w2a, const float* __restrict__ w2b,
        const float* __restrict__ w3a, const float* __restrict__ w3b,
        ushort_t* __restrict__ o1a, ushort_t* __restrict__ o1b,
        ushort_t* __restrict__ o2a, ushort_t* __restrict__ o2b,
        ushort_t* __restrict__ o3a, ushort_t* __restrict__ o3b) {
    int t = blockIdx.x * 256 + threadIdx.x;
    const float* W; ushort_t* O; int K, N, i;
    if      (t <  49152) { W = w1a; O = o1a; K = 384; N = 128; i = t; }
    else if (t <  65536) { W = w1b; O = o1b; K = 128; N = 128; i = t - 49152; }
    else if (t <  81920) { W = w2a; O = o2a; K = 128; N = 128; i = t - 65536; }
    else if (t <  98304) { W = w2b; O = o2b; K = 128; N = 128; i = t - 81920; }
    else if (t < 114688) { W = w3a; O = o3a; K = 128; N = 128; i = t - 98304; }
    else if (t < 122880) { W = w3b; O = o3b; K = 128; N = 64;  i = t - 114688; }
    else return;
    int k = i / N, c = i % N;
    O[c * K + k] = f2b(W[i]);
}

// ---------------- D1: C[M,128] = bf16(A fp32 [M,384]) @ Wt ------------------
// Full-K burst staging: entire 64x384 tile -> LDS bf16 in one shot, ONE
// barrier pair, then 12 unrolled MFMA k-steps (B from L2-hot Wt).
__global__ __launch_bounds__(256, 3) void gemm1_k(const float* __restrict__ A,
                                                  const ushort_t* __restrict__ Wt,
                                                  ushort_t* __restrict__ C, int M) {
    constexpr int BM = 64;
    constexpr int K = 384;
    __shared__ ushort_t Al[BM * LDA1];

    const int tid  = threadIdx.x;
    const int lane = tid & 63;
    const int wid  = tid >> 6;
    const int wrow = wid >> 1;              // 0..1 (32-row halves)
    const int wcol = wid & 1;               // 0..1 (64-col halves)
    const int l15  = lane & 15;
    const int kg   = lane >> 4;
    const int row0 = blockIdx.x * BM;

    // ---- stage whole A tile: 6144 float4s, 24/thread, all independent ----
    #pragma unroll
    for (int p = 0; p < 24; ++p) {
        int idx = tid + p * 256;
        int r = idx / 96;                   // 0..63
        int c = idx % 96;                   // float4 units within row
        int gr = row0 + r;
        if (gr > M - 1) gr = M - 1;
        float4 v = *reinterpret_cast<const float4*>(A + (size_t)gr * K + c * 4);
        uint_t u0 = (uint_t)f2b(v.x) | ((uint_t)f2b(v.y) << 16);
        uint_t u1 = (uint_t)f2b(v.z) | ((uint_t)f2b(v.w) << 16);
        uint2* dst = reinterpret_cast<uint2*>(&Al[r * LDA1 + c * 4]);
        *dst = make_uint2(u0, u1);
    }
    __syncthreads();

    // ---- 12 MFMA k-steps, no barriers ----
    f32x4 acc[2][4];
    #pragma unroll
    for (int i = 0; i < 2; ++i)
        #pragma unroll
        for (int j = 0; j < 4; ++j)
            acc[i][j] = f32x4{0.f, 0.f, 0.f, 0.f};

    #pragma unroll
    for (int kk = 0; kk < 12; ++kk) {
        bf16x8 a0 = *reinterpret_cast<const bf16x8*>(&Al[(wrow * 32 + l15) * LDA1 + kk * 32 + kg * 8]);
        bf16x8 a1 = *reinterpret_cast<const bf16x8*>(&Al[(wrow * 32 + 16 + l15) * LDA1 + kk * 32 + kg * 8]);
        #pragma unroll
        for (int j = 0; j < 4; ++j) {
            int col = wcol * 64 + j * 16 + l15;
            bf16x8 b = *reinterpret_cast<const bf16x8*>(Wt + (size_t)col * K + kk * 32 + kg * 8);
            acc[0][j] = __builtin_amdgcn_mfma_f32_16x16x32_bf16(a0, b, acc[0][j], 0, 0, 0);
            acc[1][j] = __builtin_amdgcn_mfma_f32_16x16x32_bf16(a1, b, acc[1][j], 0, 0, 0);
        }
    }

    // ---- epilogue: stage bf16 rows in LDS, full-line coalesced store ----
    __syncthreads();
    #pragma unroll
    for (int i = 0; i < 2; ++i)
        #pragma unroll
        for (int j = 0; j < 4; ++j) {
            int col = wcol * 64 + j * 16 + l15;
            #pragma unroll
            for (int q = 0; q < 4; ++q) {
                int row = wrow * 32 + i * 16 + kg * 4 + q;
                Al[row * LDA1 + col] = f2b(acc[i][j][q]);
            }
        }
    __syncthreads();
    #pragma unroll
    for (int p = 0; p < 4; ++p) {
        int idx = tid + p * 256;
        int rr = idx >> 4, c16 = idx & 15;
        int gr = row0 + rr;
        if (gr < M)
            *reinterpret_cast<uint4*>(C + (size_t)gr * 128 + c16 * 8) =
                *reinterpret_cast<const uint4*>(&Al[rr * LDA1 + c16 * 8]);
    }
}

// ---------------- CSR build ----------------
__global__ __launch_bounds__(256) void hist_k(const int* __restrict__ dst,
                                              int* __restrict__ deg) {
    int e = blockIdx.x * 256 + threadIdx.x;
    if (e < N_EDGES) atomicAdd(&deg[dst[e]], 1);
}

__global__ __launch_bounds__(256) void scan1_k(const int* __restrict__ deg,
                                               int* __restrict__ tmp,
                                               int* __restrict__ bsum) {
    __shared__ int s[256];
    int i = blockIdx.x * 256 + threadIdx.x;
    int t = threadIdx.x;
    s[t] = (i < N_NODES) ? deg[i] : 0;
    __syncthreads();
    for (int off = 1; off < 256; off <<= 1) {
        int v = (t >= off) ? s[t - off] : 0;
        __syncthreads();
        s[t] += v;
        __syncthreads();
    }
    if (i < N_NODES) tmp[i] = s[t];
    if (t == 255) bsum[blockIdx.x] = s[255];
}

__global__ __launch_bounds__(512) void scan2_k(int* __restrict__ bsum) {
    __shared__ int s[512];
    int t = threadIdx.x;
    s[t] = (t < NB_SCAN) ? bsum[t] : 0;
    __syncthreads();
    for (int off = 1; off < 512; off <<= 1) {
        int v = (t >= off) ? s[t - off] : 0;
        __syncthreads();
        s[t] += v;
        __syncthreads();
    }
    if (t < NB_SCAN) bsum[t] = s[t];
}

__global__ __launch_bounds__(256) void scan3_k(const int* __restrict__ tmp,
                                               const int* __restrict__ deg,
                                               const int* __restrict__ bsum,
                                               int* __restrict__ row_start) {
    int i = blockIdx.x * 256 + threadIdx.x;
    if (i >= N_NODES) return;
    int boff = (blockIdx.x > 0) ? bsum[blockIdx.x - 1] : 0;
    row_start[i] = tmp[i] - deg[i] + boff;
}

__global__ __launch_bounds__(256) void fill_k(const int* __restrict__ src,
                                              const int* __restrict__ dst,
                                              int* __restrict__ row_start,
                                              int* __restrict__ csr_src) {
    int e = blockIdx.x * 256 + threadIdx.x;
    if (e >= N_EDGES) return;
    int idx = atomicAdd(&row_start[dst[e]], 1);
    csr_src[idx] = src[e];
}

// ---------- gather + BN + ReLU, one wave per node, 4 neighbor slots ----------
__global__ __launch_bounds__(256) void gather_bn_k(
        const ushort_t* __restrict__ Yin,
        const int* __restrict__ csr, const int* __restrict__ rend,
        const int* __restrict__ deg,
        const float* __restrict__ epsp, const float* __restrict__ ba,
        const float* __restrict__ g, const float* __restrict__ be,
        const float* __restrict__ mm, const float* __restrict__ vv,
        ushort_t* __restrict__ H, int nwaves) {
    const int gwid = (blockIdx.x * 256 + threadIdx.x) >> 6;
    const int lane = threadIdx.x & 63;
    const int l15  = lane & 15;
    const int slot = lane >> 4;
    const int c0   = l15 * 8;

    float ep = 1.0f + epsp[0];
    float sc[8], sh[8];
    #pragma unroll
    for (int jj = 0; jj < 8; ++jj) {
        int c = c0 + jj;
        float s = g[c] * rsqrtf(vv[c] + 1e-5f);
        sc[jj] = s;
        sh[jj] = (ba[c] - mm[c]) * s + be[c];
    }

    for (int node = gwid; node < N_NODES; node += nwaves) {
        int end = rend[node];
        int d = deg[node];
        int st = end - d;
        uint4 ow = *reinterpret_cast<const uint4*>(Yin + (size_t)node * 128 + c0);
        int nlim = (d > 64) ? 64 : d;
        int nb = (lane < nlim) ? csr[st + lane] : 0;

        float acc[8] = {0.f, 0.f, 0.f, 0.f, 0.f, 0.f, 0.f, 0.f};
        for (int j0 = 0; j0 < nlim; j0 += 8) {
            int jA = j0 + slot;
            int jB = j0 + 4 + slot;
            int ia = __shfl(nb, jA & 63);
            int ib = __shfl(nb, jB & 63);
            uint4 wa = *reinterpret_cast<const uint4*>(Yin + (size_t)ia * 128 + c0);
            uint4 wb = *reinterpret_cast<const uint4*>(Yin + (size_t)ib * 128 + c0);
            float fa = (jA < nlim) ? 1.f : 0.f;
            float fb = (jB < nlim) ? 1.f : 0.f;
            uint_t ua[4] = {wa.x, wa.y, wa.z, wa.w};
            uint_t ub[4] = {wb.x, wb.y, wb.z, wb.w};
            #pragma unroll
            for (int p = 0; p < 4; ++p) {
                acc[2 * p]     += fa * b2f((ushort_t)(ua[p] & 0xffff));
                acc[2 * p + 1] += fa * b2f((ushort_t)(ua[p] >> 16));
                acc[2 * p]     += fb * b2f((ushort_t)(ub[p] & 0xffff));
                acc[2 * p + 1] += fb * b2f((ushort_t)(ub[p] >> 16));
            }
        }
        for (int j = st + 64; j < end; ++j) {
            if (slot == 0) {
                int idx = csr[j];
                uint4 w = *reinterpret_cast<const uint4*>(Yin + (size_t)idx * 128 + c0);
                uint_t uw[4] = {w.x, w.y, w.z, w.w};
                #pragma unroll
                for (int p = 0; p < 4; ++p) {
                    acc[2 * p]     += b2f((ushort_t)(uw[p] & 0xffff));
                    acc[2 * p + 1] += b2f((ushort_t)(uw[p] >> 16));
                }
            }
        }
        #pragma unroll
        for (int jj = 0; jj < 8; ++jj) {
            acc[jj] += __shfl_xor(acc[jj], 16);
            acc[jj] += __shfl_xor(acc[jj], 32);
        }
        uint_t uo[4] = {ow.x, ow.y, ow.z, ow.w};
        ushort_t rr[8];
        #pragma unroll
        for (int p = 0; p < 4; ++p) {
            float o0 = b2f((ushort_t)(uo[p] & 0xffff));
            float o1 = b2f((ushort_t)(uo[p] >> 16));
            float t0 = sc[2 * p] * (ep * o0 + acc[2 * p]) + sh[2 * p];
            float t1 = sc[2 * p + 1] * (ep * o1 + acc[2 * p + 1]) + sh[2 * p + 1];
            rr[2 * p]     = f2b(fmaxf(t0, 0.f));
            rr[2 * p + 1] = f2b(fmaxf(t1, 0.f));
        }
        if (slot == 0) {
            uint4 packed;
            packed.x = (uint_t)rr[0] | ((uint_t)rr[1] << 16);
            packed.y = (uint_t)rr[2] | ((uint_t)rr[3] << 16);
            packed.z = (uint_t)rr[4] | ((uint_t)rr[5] << 16);
            packed.w = (uint_t)rr[6] | ((uint_t)rr[7] << 16);
            *reinterpret_cast<uint4*>(H + (size_t)node * 128 + c0) = packed;
        }
    }
}

// -------- MLP pair: X=relu(H@Wb+bias); TAIL? pool(X) : Yout = X@Wa2 ----------
template<bool TAIL>
__global__ __launch_bounds__(256) void mlp_k(const ushort_t* __restrict__ Hin,
                                             const ushort_t* __restrict__ Wb,
                                             const float* __restrict__ bias1,
                                             const ushort_t* __restrict__ Wa2,
                                             ushort_t* __restrict__ Yout,
                                             const int* __restrict__ batch,
                                             float* __restrict__ pooled, int M) {
    constexpr int BM = 64;
    constexpr int NJ1 = TAIL ? 2 : 4;       // N1 = 64 or 128
    __shared__ ushort_t Hl[BM * LDP];
    __shared__ ushort_t Xl[BM * LDP];       // also f32 pool staging [64][FLDP]
    float* Fl = (float*)Xl;

    const int tid  = threadIdx.x;
    const int lane = tid & 63;
    const int wid  = tid >> 6;
    const int wrow = wid >> 1;
    const int wcol = wid & 1;
    const int l15  = lane & 15;
    const int kg   = lane >> 4;
    const int row0 = blockIdx.x * BM;

    #pragma unroll
    for (int p = 0; p < 4; ++p) {
        int idx = tid + p * 256;
        int r = idx >> 4, c16 = idx & 15;
        int gr = row0 + r;
        if (gr > M - 1) gr = M - 1;
        *reinterpret_cast<uint4*>(&Hl[r * LDP + c16 * 8]) =
            *reinterpret_cast<const uint4*>(Hin + (size_t)gr * 128 + c16 * 8);
    }
    __syncthreads();

    f32x4 acc1[2][NJ1];
    #pragma unroll
    for (int i = 0; i < 2; ++i)
        #pragma unroll
        for (int j = 0; j < NJ1; ++j)
            acc1[i][j] = f32x4{0.f, 0.f, 0.f, 0.f};
    #pragma unroll
    for (int kk = 0; kk < 4; ++kk) {
        bf16x8 a0 = *reinterpret_cast<const bf16x8*>(&Hl[(wrow * 32 + l15) * LDP + kk * 32 + kg * 8]);
        bf16x8 a1 = *reinterpret_cast<const bf16x8*>(&Hl[(wrow * 32 + 16 + l15) * LDP + kk * 32 + kg * 8]);
        #pragma unroll
        for (int j = 0; j < NJ1; ++j) {
            int col = wcol * (16 * NJ1) + j * 16 + l15;
            bf16x8 b = *reinterpret_cast<const bf16x8*>(Wb + (size_t)col * 128 + kk * 32 + kg * 8);
            acc1[0][j] = __builtin_amdgcn_mfma_f32_16x16x32_bf16(a0, b, acc1[0][j], 0, 0, 0);
            acc1[1][j] = __builtin_amdgcn_mfma_f32_16x16x32_bf16(a1, b, acc1[1][j], 0, 0, 0);
        }
    }

    if constexpr (TAIL) {
        #pragma unroll
        for (int i = 0; i < 2; ++i)
            #pragma unroll
            for (int j = 0; j < NJ1; ++j) {
                int col = wcol * 32 + j * 16 + l15;
                float bi = bias1[col];
                #pragma unroll
                for (int q = 0; q < 4; ++q) {
                    int row = wrow * 32 + i * 16 + kg * 4 + q;
                    Fl[row * FLDP + col] = fmaxf(acc1[i][j][q] + bi, 0.f);
                }
            }
        __syncthreads();
        int col = tid & 63;
        int qq  = tid >> 6;
        float a = 0.f;
        int cur = -1;
        for (int rr = 0; rr < 16; ++rr) {
            int r = qq * 16 + rr;
            int gr = row0 + r;
            if (gr >= M) break;
            int b = batch[gr];
            if (b != cur) {
                if (cur >= 0) atomicAdd(&pooled[cur * 64 + col], a);
                a = 0.f;
                cur = b;
            }
            a += Fl[r * FLDP + col];
        }
        if (cur >= 0) atomicAdd(&pooled[cur * 64 + col], a);
    } else {
        #pragma unroll
        for (int i = 0; i < 2; ++i)
            #pragma unroll
            for (int j = 0; j < NJ1; ++j) {
                int col = wcol * 64 + j * 16 + l15;
                float bi = bias1[col];
                #pragma unroll
                for (int q = 0; q < 4; ++q) {
                    int row = wrow * 32 + i * 16 + kg * 4 + q;
                    Xl[row * LDP + col] = f2b(fmaxf(acc1[i][j][q] + bi, 0.f));
                }
            }
        __syncthreads();

        f32x4 acc2[2][4];
        #pragma unroll
        for (int i = 0; i < 2; ++i)
            #pragma unroll
            for (int j = 0; j < 4; ++j)
                acc2[i][j] = f32x4{0.f, 0.f, 0.f, 0.f};
        #pragma unroll
        for (int kk = 0; kk < 4; ++kk) {
            bf16x8 a0 = *reinterpret_cast<const bf16x8*>(&Xl[(wrow * 32 + l15) * LDP + kk * 32 + kg * 8]);
            bf16x8 a1 = *reinterpret_cast<const bf16x8*>(&Xl[(wrow * 32 + 16 + l15) * LDP + kk * 32 + kg * 8]);
            #pragma unroll
            for (int j = 0; j < 4; ++j) {
                int col = wcol * 64 + j * 16 + l15;
                bf16x8 b = *reinterpret_cast<const bf16x8*>(Wa2 + (size_t)col * 128 + kk * 32 + kg * 8);
                acc2[0][j] = __builtin_amdgcn_mfma_f32_16x16x32_bf16(a0, b, acc2[0][j], 0, 0, 0);
                acc2[1][j] = __builtin_amdgcn_mfma_f32_16x16x32_bf16(a1, b, acc2[1][j], 0, 0, 0);
            }
        }
        #pragma unroll
        for (int i = 0; i < 2; ++i)
            #pragma unroll
            for (int j = 0; j < 4; ++j) {
                int col = wcol * 64 + j * 16 + l15;
                #pragma unroll
                for (int q = 0; q < 4; ++q) {
                    int row = wrow * 32 + i * 16 + kg * 4 + q;
                    Hl[row * LDP + col] = f2b(acc2[i][j][q]);
                }
            }
        __syncthreads();
        #pragma unroll
        for (int p = 0; p < 4; ++p) {
            int idx = tid + p * 256;
            int r = idx >> 4, c16 = idx & 15;
            int gr = row0 + r;
            if (gr < M)
                *reinterpret_cast<uint4*>(Yout + (size_t)gr * 128 + c16 * 8) =
                    *reinterpret_cast<const uint4*>(&Hl[r * LDP + c16 * 8]);
        }
    }
}

// ---------------- classifier ----------------
__global__ __launch_bounds__(256) void classifier_k(const float* __restrict__ pooled,
                                                    const float* __restrict__ wc,
                                                    const float* __restrict__ bc,
                                                    float* __restrict__ out) {
    int t = threadIdx.x;
    int gidx = t >> 1, c = t & 1;
    float s = bc[c];
    #pragma unroll
    for (int k = 0; k < 64; ++k)
        s += pooled[gidx * 64 + k] * wc[k * 2 + c];
    out[gidx * 2 + c] = s;
}

extern "C" void kernel_launch(void* const* d_in, const int* in_sizes, int n_in,
                              void* d_out, int out_size, void* d_ws, size_t ws_size,
                              hipStream_t stream) {
    const float* x     = (const float*)d_in[0];
    const int*   ei    = (const int*)d_in[1];
    const int*   src   = ei;
    const int*   dst   = ei + N_EDGES;
    const int*   batch = (const int*)d_in[2];
    const float* eps1 = (const float*)d_in[3];
    const float* w1a  = (const float*)d_in[4];
    const float* b1a  = (const float*)d_in[5];
    const float* g1   = (const float*)d_in[6];
    const float* be1  = (const float*)d_in[7];
    const float* m1   = (const float*)d_in[8];
    const float* v1   = (const float*)d_in[9];
    const float* w1b  = (const float*)d_in[10];
    const float* b1b  = (const float*)d_in[11];
    const float* eps2 = (const float*)d_in[12];
    const float* w2a  = (const float*)d_in[13];
    const float* b2a  = (const float*)d_in[14];
    const float* g2   = (const float*)d_in[15];
    const float* be2  = (const float*)d_in[16];
    const float* m2   = (const float*)d_in[17];
    const float* v2   = (const float*)d_in[18];
    const float* w2b  = (const float*)d_in[19];
    const float* b2b  = (const float*)d_in[20];
    const float* eps3 = (const float*)d_in[21];
    const float* w3a  = (const float*)d_in[22];
    const float* b3a  = (const float*)d_in[23];
    const float* g3   = (const float*)d_in[24];
    const float* be3  = (const float*)d_in[25];
    const float* m3   = (const float*)d_in[26];
    const float* v3   = (const float*)d_in[27];
    const float* w3b  = (const float*)d_in[28];
    const float* b3b  = (const float*)d_in[29];
    const float* wc   = (const float*)d_in[30];
    const float* bc   = (const float*)d_in[31];
    float* out = (float*)d_out;

    // workspace layout
    ushort_t* Y = (ushort_t*)d_ws;             // [100000,128] bf16
    ushort_t* H = Y + 12800000;                // [100000,128] bf16
    ushort_t* wt1a = H + 12800000;             // 384*128
    ushort_t* wt1b = wt1a + 49152;             // 128*128
    ushort_t* wt2a = wt1b + 16384;
    ushort_t* wt2b = wt2a + 16384;
    ushort_t* wt3a = wt2b + 16384;
    ushort_t* wt3b = wt3a + 16384;             // 64*128
    float* pooled = (float*)(wt3b + 8192);     // [128,64]
    int* ideg = (int*)(pooled + 8192);         // [100000]
    int* irow = ideg + N_NODES;
    int* itmp = irow + N_NODES;
    int* icsr = itmp + N_NODES;                // [800000]
    int* ibsum = icsr + N_EDGES;               // [391]

    const int M = N_NODES;
    const int gGemm = (M + 63) / 64;           // 1563
    const int gEdge = (N_EDGES + 255) / 256;   // 3125
    const int gNode = NB_SCAN;                 // 391
    const int gGath = 2048;                    // 8192 waves
    const int nwaves = gGath * 4;

    // ---- all weight transposes (one dispatch) ----
    wt_all_k<<<480, 256, 0, stream>>>(w1a, w1b, w2a, w2b, w3a, w3b,
                                      wt1a, wt1b, wt2a, wt2b, wt3a, wt3b);

    // ---- build CSR ----
    hipMemsetAsync(ideg, 0, N_NODES * sizeof(int), stream);
    hist_k<<<gEdge, 256, 0, stream>>>(dst, ideg);
    scan1_k<<<gNode, 256, 0, stream>>>(ideg, itmp, ibsum);
    scan2_k<<<1, 512, 0, stream>>>(ibsum);
    scan3_k<<<gNode, 256, 0, stream>>>(itmp, ideg, ibsum, irow);
    fill_k<<<gEdge, 256, 0, stream>>>(src, dst, irow, icsr);
    hipMemsetAsync(pooled, 0, (size_t)N_GRAPHS * 64 * sizeof(float), stream);

    // ---- D1: Y1 = x @ w1a ----
    gemm1_k<<<gGemm, 256, 0, stream>>>(x, wt1a, Y, M);

    // ---- layer 1 ----
    gather_bn_k<<<gGath, 256, 0, stream>>>(Y, icsr, irow, ideg, eps1, b1a, g1, be1, m1, v1, H, nwaves);
    mlp_k<false><<<gGemm, 256, 0, stream>>>(H, wt1b, b1b, wt2a, Y, nullptr, nullptr, M);

    // ---- layer 2 ----
    gather_bn_k<<<gGath, 256, 0, stream>>>(Y, icsr, irow, ideg, eps2, b2a, g2, be2, m2, v2, H, nwaves);
    mlp_k<false><<<gGemm, 256, 0, stream>>>(H, wt2b, b2b, wt3a, Y, nullptr, nullptr, M);

    // ---- layer 3 ----
    gather_bn_k<<<gGath, 256, 0, stream>>>(Y, icsr, irow, ideg, eps3, b3a, g3, be3, m3, v3, H, nwaves);
    mlp_k<true><<<gGemm, 256, 0, stream>>>(H, wt3b, b3b, nullptr, nullptr, batch, pooled, M);

    // ---- classifier ----
    classifier_k<<<1, 256, 0, stream>>>(pooled, wc, bc, out);
}